// Round 7
// baseline (675.566 us; speedup 1.0000x reference)
//
#include <hip/hip_runtime.h>
#include <hip/hip_bf16.h>

using bf16 = __hip_bfloat16;
typedef __attribute__((ext_vector_type(8))) short bf16x8;
typedef __attribute__((ext_vector_type(4))) float f32x4;

// Shapes fixed: B=2, S=2048, D=1024, H=16, hd=64, F=2048. Global I/O fp32.
// ws = 16 MB (8M bf16), d_out doubles as scratch (obB, 8M bf16 / 4M fp32).
//
// ws elems:  q0[0:2M) k0[2M:4M) q1[4M:6M) k1[6M:8M)     (attention phase)
//            WoT[0:1M)  -> x2[4M:8M)                    (Wo phase, q dead)
//            W12q[0:1M) sbq[1M:3M) W3q[3M:3.5M) tail[3.5M:4M): stats/bias
// obB elems: vt0[0:2M) vt1[2M:4M) h[4M:6M) w[6M:8M); attnout[4M:8M)
// Final FFN GEMMs write fp32 d_out (all of obB) -- at that point every live
// operand (sbq, W3q, x2, stats, bias) is in ws. nh=0 writes x2+acc, nh>0
// does in-place += (same-idx RMW, race-free).

__device__ inline float toF(float x) { return x; }
__device__ inline float toF(bf16 x) { return __bfloat162float(x); }
__device__ inline void  stV(float* p, float v) { *p = v; }
__device__ inline void  stV(bf16* p, float v) { *p = __float2bfloat16(v); }

__device__ __forceinline__ void unpack8(uint4 u, float* f) {
    f[0] = __uint_as_float(u.x << 16); f[1] = __uint_as_float(u.x & 0xffff0000u);
    f[2] = __uint_as_float(u.y << 16); f[3] = __uint_as_float(u.y & 0xffff0000u);
    f[4] = __uint_as_float(u.z << 16); f[5] = __uint_as_float(u.z & 0xffff0000u);
    f[6] = __uint_as_float(u.w << 16); f[7] = __uint_as_float(u.w & 0xffff0000u);
}

__device__ __forceinline__ uint4 packbf8(const float* f) {
    union { unsigned short u[8]; uint4 v; } r;
#pragma unroll
    for (int i = 0; i < 8; i++) {
        bf16 b = __float2bfloat16(f[i]);
        r.u[i] = *(unsigned short*)&b;
    }
    return r.v;
}

__device__ __forceinline__ void gl_lds16(const void* g, void* l) {
    __builtin_amdgcn_global_load_lds(
        (__attribute__((address_space(1))) void*)g,
        (__attribute__((address_space(3))) void*)l, 16, 0, 0);
}

// ---------------------------------------------------------------------------
// LayerNorm (LN1): one block per row, D=1024. fp32 in -> bf16 out.
// ---------------------------------------------------------------------------
__global__ __launch_bounds__(256) void ln_kernel(
    const float* __restrict__ x, const float* __restrict__ g,
    const float* __restrict__ b, bf16* __restrict__ out)
{
    const int D = 1024;
    int row = blockIdx.x;
    int tid = threadIdx.x;
    const float* xr = x + (size_t)row * D;

    float vals[4];
    float sum = 0.f, sumsq = 0.f;
#pragma unroll
    for (int i = 0; i < 4; i++) {
        float v = xr[tid + i * 256];
        vals[i] = v; sum += v; sumsq += v * v;
    }
#pragma unroll
    for (int off = 32; off > 0; off >>= 1) {
        sum += __shfl_xor(sum, off);
        sumsq += __shfl_xor(sumsq, off);
    }
    __shared__ float s1[4], s2[4];
    int wave = tid >> 6, lane = tid & 63;
    if (lane == 0) { s1[wave] = sum; s2[wave] = sumsq; }
    __syncthreads();
    sum = s1[0] + s1[1] + s1[2] + s1[3];
    sumsq = s2[0] + s2[1] + s2[2] + s2[3];

    float mu = sum * (1.f / D);
    float var = sumsq * (1.f / D) - mu * mu;
    float rstd = rsqrtf(var + 1e-5f);

    bf16* orow = out + (size_t)row * D;
#pragma unroll
    for (int i = 0; i < 4; i++) {
        int c = tid + i * 256;
        orow[c] = __float2bfloat16((vals[i] - mu) * rstd * g[c] + b[c]);
    }
}

// ---------------------------------------------------------------------------
// LN2 stats: x2 bf16 [4096][1024] -> stats[row] = {mu, rstd}
// ---------------------------------------------------------------------------
__global__ __launch_bounds__(256) void ln2stats_kernel(
    const bf16* __restrict__ x2, float* __restrict__ stats)
{
    const int D = 1024;
    int row = blockIdx.x;
    int tid = threadIdx.x;
    const bf16* xr = x2 + (size_t)row * D;

    float sum = 0.f, sumsq = 0.f;
#pragma unroll
    for (int i = 0; i < 4; i++) {
        float v = toF(xr[tid + i * 256]);
        sum += v; sumsq += v * v;
    }
#pragma unroll
    for (int off = 32; off > 0; off >>= 1) {
        sum += __shfl_xor(sum, off);
        sumsq += __shfl_xor(sumsq, off);
    }
    __shared__ float s1[4], s2[4];
    int wave = tid >> 6, lane = tid & 63;
    if (lane == 0) { s1[wave] = sum; s2[wave] = sumsq; }
    __syncthreads();
    if (tid == 0) {
        sum = s1[0] + s1[1] + s1[2] + s1[3];
        sumsq = s2[0] + s2[1] + s2[2] + s2[3];
        float mu = sum * (1.f / D);
        float var = sumsq * (1.f / D) - mu * mu;
        stats[row * 2] = mu;
        stats[row * 2 + 1] = rsqrtf(var + 1e-5f);
    }
}

// ---------------------------------------------------------------------------
// bias[j] = sum_d b[d] * W[d*2048 + j], j < 2048  (ln2_b @ W fold)
// ---------------------------------------------------------------------------
__global__ __launch_bounds__(256) void biasw_kernel(
    const float* __restrict__ b, const float* __restrict__ W,
    float* __restrict__ bias)
{
    int j = blockIdx.x * 256 + threadIdx.x;
    float s = 0.f;
    for (int d = 0; d < 1024; d++) s += b[d] * W[(size_t)d * 2048 + j];
    bias[j] = s;
}

// ---------------------------------------------------------------------------
// Transpose+convert: in fp32, per z-slice [R][C] with row stride ldin ->
// out bf16 [C][R] (out row stride R). Optional per-input-row scale[r].
// ---------------------------------------------------------------------------
__global__ __launch_bounds__(256) void tconv_kernel(
    const float* __restrict__ in, bf16* __restrict__ out,
    int R, int C, int ldin, const float* __restrict__ scale)
{
    __shared__ float t[32][33];
    int hh = blockIdx.z;
    const float* ip = in + (size_t)hh * R * ldin;
    bf16* op = out + (size_t)hh * C * R;
    int c0 = blockIdx.x * 32, r0 = blockIdx.y * 32;
    int tx = threadIdx.x & 31, ty = threadIdx.x >> 5;  // ty 0..7
#pragma unroll
    for (int i = 0; i < 4; i++) {
        int r = r0 + ty + 8 * i;
        float v = ip[(size_t)r * ldin + c0 + tx];
        if (scale) v *= scale[r];
        t[ty + 8 * i][tx] = v;
    }
    __syncthreads();
#pragma unroll
    for (int i = 0; i < 4; i++)
        op[(size_t)(c0 + ty + 8 * i) * R + r0 + tx] = __float2bfloat16(t[tx][ty + 8 * i]);
}

// ---------------------------------------------------------------------------
// MFMA GEMM: C[M,N] = A[M,K](bf16) @ BT[N,K](bf16), fp32 accum.
// 128x128 tile, BK=32, 4 waves (2x2), 4x4 16x16 MFMA subtiles per wave.
// MODE 1: QK+RoPE scatter (z in {0,1}: BT+=z<<20, C=Cbase+z<<21; [h][s][64])
// MODE 5: V^T scatter: Vt[h][kk][s] (packed 4-row 8B stores)
// MODE 2: C bf16 = acc + resF32
// MODE 4: C f32  = acc + resBf16
// MODE 6: C f32 += acc (in-place RMW)
// ---------------------------------------------------------------------------
template <int MODE>
__global__ __launch_bounds__(256) void mfma_gemm(
    const bf16* __restrict__ A, const bf16* __restrict__ BT0,
    void* __restrict__ Cv, const void* __restrict__ resv,
    int M, int N, int K)
{
    __shared__ bf16 As[128 * 32];
    __shared__ bf16 Bs[128 * 32];
    int tid = threadIdx.x, lane = tid & 63, w = tid >> 6;
    int wm = w >> 1, wn = w & 1;
    int m0 = blockIdx.y * 128, n0 = blockIdx.x * 128;

    const bf16* BT = BT0;
    bf16* Cq = (bf16*)Cv;
    if (MODE == 1) {
        int z = blockIdx.z;
        BT = BT0 + ((size_t)z << 20);
        Cq = (bf16*)Cv + ((size_t)z << 21);
    }

    int srow = lane >> 2, scol = (lane & 3) * 8;
    const bf16* Ag = A + (size_t)(m0 + w * 32 + srow) * K + scol;
    const bf16* Bg = BT + (size_t)(n0 + w * 32 + srow) * K + scol;
    unsigned offAB = (unsigned)__builtin_amdgcn_readfirstlane(w * 2048);
    char* As_c = (char*)As;
    char* Bs_c = (char*)Bs;

    f32x4 acc[4][4];
#pragma unroll
    for (int i = 0; i < 4; i++)
#pragma unroll
        for (int j = 0; j < 4; j++) acc[i][j] = (f32x4){0.f, 0.f, 0.f, 0.f};

    for (int k0 = 0; k0 < K; k0 += 32) {
        gl_lds16(Ag + k0,                  As_c + offAB);
        gl_lds16(Ag + k0 + (size_t)16 * K, As_c + offAB + 1024);
        gl_lds16(Bg + k0,                  Bs_c + offAB);
        gl_lds16(Bg + k0 + (size_t)16 * K, Bs_c + offAB + 1024);
        __syncthreads();

        bf16x8 af[4], bfr[4];
#pragma unroll
        for (int i = 0; i < 4; i++)
            af[i] = *(const bf16x8*)&As[(wm * 64 + i * 16 + (lane & 15)) * 32 + (lane >> 4) * 8];
#pragma unroll
        for (int j = 0; j < 4; j++)
            bfr[j] = *(const bf16x8*)&Bs[(wn * 64 + j * 16 + (lane & 15)) * 32 + (lane >> 4) * 8];
#pragma unroll
        for (int i = 0; i < 4; i++)
#pragma unroll
            for (int j = 0; j < 4; j++)
                acc[i][j] = __builtin_amdgcn_mfma_f32_16x16x32_bf16(af[i], bfr[j], acc[i][j], 0, 0, 0);
        __syncthreads();
    }

    int rbase = (lane >> 4) * 4;
    int cidx = lane & 15;
#pragma unroll
    for (int i = 0; i < 4; i++) {
#pragma unroll
        for (int j = 0; j < 4; j++) {
            int col = n0 + wn * 64 + j * 16 + cidx;
            if (MODE == 5) {
                // pack 4 consecutive rows (s) into one 8B store
                int h = col >> 6, kk = col & 63;
                int row0 = m0 + wm * 64 + i * 16 + rbase;
                union { unsigned short u[4]; uint2 v; } pk;
#pragma unroll
                for (int r = 0; r < 4; r++) {
                    bf16 bv = __float2bfloat16(acc[i][j][r]);
                    pk.u[r] = *(unsigned short*)&bv;
                }
                *(uint2*)(Cq + ((size_t)(h * 64 + kk) * 2048 + row0)) = pk.v;
            } else {
#pragma unroll
                for (int r = 0; r < 4; r++) {
                    int row = m0 + wm * 64 + i * 16 + rbase + r;
                    float v = acc[i][j][r];
                    size_t idx = (size_t)row * N + col;
                    if (MODE == 1) {
                        int h = col >> 6, kk = col & 63;
                        float other = __shfl_xor(v, 1);
                        float p = (float)(kk >> 1);
                        float theta = __expf(p * -0.5756462732485114f); // ln(1e4)/16
                        float ang = (float)row * theta;
                        float c, sn; __sincosf(ang, &sn, &c);
                        float outv = (kk & 1) ? (v * c + other * sn) : (v * c - other * sn);
                        Cq[((size_t)h * 2048 + row) * 64 + kk] = __float2bfloat16(outv);
                    } else if (MODE == 2) {
                        v += ((const float*)resv)[idx];
                        ((bf16*)Cv)[idx] = __float2bfloat16(v);
                    } else if (MODE == 4) {
                        v += __bfloat162float(((const bf16*)resv)[idx]);
                        ((float*)Cv)[idx] = v;
                    } else { // MODE 6
                        ((float*)Cv)[idx] += v;
                    }
                }
            }
        }
    }
}

// ---------------------------------------------------------------------------
// Dual GEMM + fused LN2 staging + SwiGLU epilogue.
// sbq[M,512] = silu(hn@B1T + bias1) * (hn@B2T + bias2), hn = (x2-mu)*rstd.
// Tile 128m x 64n, BK=32, 4 waves 2x2 (wave = 64m x 32n, 4x2 subtiles x2 B).
// ---------------------------------------------------------------------------
__global__ __launch_bounds__(256) void dual_gemm_ln(
    const bf16* __restrict__ x2, const float* __restrict__ stats,
    const bf16* __restrict__ B1T, const bf16* __restrict__ B2T,
    const float* __restrict__ bias1, const float* __restrict__ bias2,
    bf16* __restrict__ sbq)
{
    __shared__ bf16 As[128 * 40];          // padded ld=40
    __shared__ bf16 B1s[64 * 32];
    __shared__ bf16 B2s[64 * 32];
    int tid = threadIdx.x, lane = tid & 63, w = tid >> 6;
    int wm = w >> 1, wn = w & 1;
    int m0 = blockIdx.y * 128, n0 = blockIdx.x * 64;
    const int K = 1024, NQ = 512;

    int arow = tid >> 1, ah = tid & 1;     // A staging: row, 16-elem half
    int srow = lane >> 2, scol = (lane & 3) * 8;
    const bf16* B1g = B1T + (size_t)(n0 + w * 16 + srow) * K + scol;
    const bf16* B2g = B2T + (size_t)(n0 + w * 16 + srow) * K + scol;
    unsigned offB = (unsigned)__builtin_amdgcn_readfirstlane(w * 1024);
    char* B1s_c = (char*)B1s;
    char* B2s_c = (char*)B2s;

    float mu = stats[(m0 + arow) * 2];
    float rs = stats[(m0 + arow) * 2 + 1];

    f32x4 acc1[4][2], acc2[4][2];
#pragma unroll
    for (int i = 0; i < 4; i++)
#pragma unroll
        for (int j = 0; j < 2; j++) {
            acc1[i][j] = (f32x4){0.f, 0.f, 0.f, 0.f};
            acc2[i][j] = (f32x4){0.f, 0.f, 0.f, 0.f};
        }

    for (int k0 = 0; k0 < K; k0 += 32) {
        // A: VALU-staged LN2-normalized x2
        const uint4* xs = (const uint4*)(x2 + (size_t)(m0 + arow) * K + k0 + ah * 16);
        uint4 u0 = xs[0], u1 = xs[1];
        float f[16]; unpack8(u0, f); unpack8(u1, f + 8);
#pragma unroll
        for (int i = 0; i < 16; i++) f[i] = (f[i] - mu) * rs;
        gl_lds16(B1g + k0, B1s_c + offB);
        gl_lds16(B2g + k0, B2s_c + offB);
        uint4 p0 = packbf8(f), p1 = packbf8(f + 8);
        *(uint4*)&As[arow * 40 + ah * 16] = p0;
        *(uint4*)&As[arow * 40 + ah * 16 + 8] = p1;
        __syncthreads();

        bf16x8 af[4], b1f[2], b2f[2];
#pragma unroll
        for (int i = 0; i < 4; i++)
            af[i] = *(const bf16x8*)&As[(wm * 64 + i * 16 + (lane & 15)) * 40 + (lane >> 4) * 8];
#pragma unroll
        for (int j = 0; j < 2; j++) {
            b1f[j] = *(const bf16x8*)&B1s[(wn * 32 + j * 16 + (lane & 15)) * 32 + (lane >> 4) * 8];
            b2f[j] = *(const bf16x8*)&B2s[(wn * 32 + j * 16 + (lane & 15)) * 32 + (lane >> 4) * 8];
        }
#pragma unroll
        for (int i = 0; i < 4; i++)
#pragma unroll
            for (int j = 0; j < 2; j++) {
                acc1[i][j] = __builtin_amdgcn_mfma_f32_16x16x32_bf16(af[i], b1f[j], acc1[i][j], 0, 0, 0);
                acc2[i][j] = __builtin_amdgcn_mfma_f32_16x16x32_bf16(af[i], b2f[j], acc2[i][j], 0, 0, 0);
            }
        __syncthreads();
    }

    int rbase = (lane >> 4) * 4;
    int cidx = lane & 15;
#pragma unroll
    for (int i = 0; i < 4; i++) {
#pragma unroll
        for (int j = 0; j < 2; j++) {
            int col = n0 + wn * 32 + j * 16 + cidx;
            float b1 = bias1[col], b2 = bias2[col];
#pragma unroll
            for (int r = 0; r < 4; r++) {
                int row = m0 + wm * 64 + i * 16 + rbase + r;
                float u = acc1[i][j][r] + b1;
                float g2 = acc2[i][j][r] + b2;
                float sg = 1.f / (1.f + __expf(-u));
                sbq[(size_t)row * NQ + col] = __float2bfloat16(u * sg * g2);
            }
        }
    }
}

// ---------------------------------------------------------------------------
// MFMA causal flash attention, joint batches. hd=64. Fixed-max softmax
// (scores Cauchy-Schwarz-bounded ~8 after /8 scale -> no running max).
// q,k: ws layout q_b = base+b*4M (+h*128K), k_b = +2M; vt: [b][16][64][2048].
// out: attnout [4096][1024] bf16 (row = b*2048+s).
// ---------------------------------------------------------------------------
__global__ __launch_bounds__(256) void attn_kernel(
    const bf16* __restrict__ qk, const bf16* __restrict__ vt,
    bf16* __restrict__ o)
{
    const int S = 2048;
    __shared__ bf16 Ks[64][72];
    __shared__ bf16 Vs[64][72];
    __shared__ __align__(16) char QPbuf[64 * 72 * 2];   // Qs, then Ps overlay
    bf16 (*Qs)[72] = (bf16 (*)[72])QPbuf;
    bf16 (*Ps)[16][72] = (bf16 (*)[16][72])QPbuf;

    int qt = 31 - (int)blockIdx.x;                  // heavy blocks first
    int bh = blockIdx.y;
    int b = bh >> 4, h = bh & 15;
    int tid = threadIdx.x, lane = tid & 63, w = tid >> 6;
    int quad = lane >> 4, cidx = lane & 15;
    int m0 = qt * 64;

    const bf16* qb = qk + ((size_t)b << 22) + ((size_t)h * S + m0) * 64;
    const bf16* kb = qk + ((size_t)b << 22) + (2u << 20) + (size_t)h * S * 64;
    const bf16* vtb = vt + ((size_t)b << 21) + (size_t)h * 64 * S;

    int srow = tid >> 2;                            // 0..63
    int sg = (tid & 3) * 16;

    {   // stage Q scaled by 1/8
        const uint4* src = (const uint4*)(qb + (size_t)srow * 64 + sg);
        uint4 u0 = src[0], u1 = src[1];
        float f[16]; unpack8(u0, f); unpack8(u1, f + 8);
#pragma unroll
        for (int i = 0; i < 16; i++) f[i] *= 0.125f;
        *(uint4*)&Qs[srow][sg] = packbf8(f);
        *(uint4*)&Qs[srow][sg + 8] = packbf8(f + 8);
    }
    __syncthreads();

    bf16x8 aQ0 = *(const bf16x8*)&Qs[w * 16 + cidx][quad * 8];
    bf16x8 aQ1 = *(const bf16x8*)&Qs[w * 16 + cidx][32 + quad * 8];

    float l_i[4];
    f32x4 Oc[4];
#pragma unroll
    for (int r = 0; r < 4; r++) l_i[r] = 0.f;
#pragma unroll
    for (int j = 0; j < 4; j++) Oc[j] = (f32x4){0.f, 0.f, 0.f, 0.f};

    for (int kt = 0; kt <= qt; kt++) {
        const uint4* ksrc = (const uint4*)(kb + ((size_t)(kt * 64 + srow)) * 64 + sg);
        uint4 ka0 = ksrc[0], ka1 = ksrc[1];
        const uint4* vsrc = (const uint4*)(vtb + (size_t)srow * S + kt * 64 + sg);
        uint4 va0 = vsrc[0], va1 = vsrc[1];

        __syncthreads();
        *(uint4*)&Ks[srow][sg] = ka0; *(uint4*)&Ks[srow][sg + 8] = ka1;
        *(uint4*)&Vs[srow][sg] = va0; *(uint4*)&Vs[srow][sg + 8] = va1;
        __syncthreads();

        f32x4 sc[4];
#pragma unroll
        for (int j = 0; j < 4; j++) sc[j] = (f32x4){0.f, 0.f, 0.f, 0.f};
#pragma unroll
        for (int j = 0; j < 4; j++) {
            bf16x8 bk0 = *(const bf16x8*)&Ks[j * 16 + cidx][quad * 8];
            bf16x8 bk1 = *(const bf16x8*)&Ks[j * 16 + cidx][32 + quad * 8];
            sc[j] = __builtin_amdgcn_mfma_f32_16x16x32_bf16(aQ0, bk0, sc[j], 0, 0, 0);
            sc[j] = __builtin_amdgcn_mfma_f32_16x16x32_bf16(aQ1, bk1, sc[j], 0, 0, 0);
        }

        if (kt == qt) {
#pragma unroll
            for (int j = 0; j < 4; j++)
#pragma unroll
                for (int r = 0; r < 4; r++)
                    if (j * 16 + cidx > w * 16 + quad * 4 + r) sc[j][r] = -INFINITY;
        }

        // fixed-max softmax: p = exp(s), accumulate l per-lane, reduce at end
#pragma unroll
        for (int j = 0; j < 4; j++) {
#pragma unroll
            for (int r = 0; r < 4; r++) {
                float p = __expf(sc[j][r]);
                l_i[r] += p;
                Ps[w][quad * 4 + r][j * 16 + cidx] = __float2bfloat16(p);
            }
        }

        bf16x8 aP0 = *(const bf16x8*)&Ps[w][cidx][quad * 8];
        bf16x8 aP1 = *(const bf16x8*)&Ps[w][cidx][32 + quad * 8];
#pragma unroll
        for (int j = 0; j < 4; j++) {
            bf16x8 bv0 = *(const bf16x8*)&Vs[j * 16 + cidx][quad * 8];
            bf16x8 bv1 = *(const bf16x8*)&Vs[j * 16 + cidx][32 + quad * 8];
            Oc[j] = __builtin_amdgcn_mfma_f32_16x16x32_bf16(aP0, bv0, Oc[j], 0, 0, 0);
            Oc[j] = __builtin_amdgcn_mfma_f32_16x16x32_bf16(aP1, bv1, Oc[j], 0, 0, 0);
        }
    }

#pragma unroll
    for (int r = 0; r < 4; r++) {
        float l = l_i[r];
        l += __shfl_xor(l, 1);
        l += __shfl_xor(l, 2);
        l += __shfl_xor(l, 4);
        l += __shfl_xor(l, 8);
        float inv = 1.f / l;
        int row = b * 2048 + m0 + w * 16 + quad * 4 + r;
#pragma unroll
        for (int j = 0; j < 4; j++)
            o[(size_t)row * 1024 + h * 64 + j * 16 + cidx] = __float2bfloat16(Oc[j][r] * inv);
    }
}

// ---------------------------------------------------------------------------
extern "C" void kernel_launch(void* const* d_in, const int* in_sizes, int n_in,
                              void* d_out, int out_size, void* d_ws, size_t ws_size,
                              hipStream_t stream)
{
    const int S = 2048, D = 1024;
    const size_t E1 = 1u << 20;        // 1M elems

    const float* x    = (const float*)d_in[0];
    const float* ln1g = (const float*)d_in[1];
    const float* ln1b = (const float*)d_in[2];
    const float* Wq   = (const float*)d_in[3];
    const float* Wk   = (const float*)d_in[4];
    const float* Wv   = (const float*)d_in[5];
    const float* Wo   = (const float*)d_in[6];
    const float* ln2g = (const float*)d_in[7];
    const float* ln2b = (const float*)d_in[8];
    const float* W1   = (const float*)d_in[9];
    const float* W2   = (const float*)d_in[10];
    const float* W3   = (const float*)d_in[11];
    float* out = (float*)d_out;

    bf16* W = (bf16*)d_ws;             // 8M elems
    bf16* obB = (bf16*)d_out;          // 8M elems (scratch until final)

    // ws map
    bf16* WoT  = W;                    // [0:1M)
    bf16* x2   = W + 4 * E1;           // [4M:8M)
    bf16* W1q  = W;                    // [0:0.5M)
    bf16* W2q  = W + E1 / 2;           // [0.5M:1M)
    bf16* sbq  = W + E1;               // [1M:3M)
    bf16* W3q  = W + 3 * E1;           // [3M:3.5M)
    float* stats = (float*)(W + 3 * E1 + E1 / 2);   // 8192 f32
    float* bias1 = stats + 8192;                    // 2048 f32
    float* bias2 = bias1 + 2048;                    // 2048 f32

    // obB map (attention phase)
    bf16* vt0 = obB;                   // [0:2M)
    bf16* hB  = obB + 4 * E1;          // [4M:6M)
    bf16* wqT = obB + 6 * E1;          // [6M:7M)  (wk at +7M; wv reuses +6M)
    bf16* attnout = obB + 4 * E1;      // [4M:8M) after attn

    for (int b = 0; b < 2; b++) {
        const float* xb = x + (size_t)b * S * D;
        bf16* qkbase = W + (size_t)b * 4 * E1;      // q at +0, k at +2M
        bf16* vtb = vt0 + (size_t)b * 2 * E1;

        // LN1 -> h
        ln_kernel<<<S, 256, 0, stream>>>(xb, ln1g, ln1b, hB);
        // WqT, WkT (per-head [64][1024] slices)
        tconv_kernel<<<dim3(2, 32, 16), 256, 0, stream>>>(Wq, wqT,       1024, 64, 64, nullptr);
        tconv_kernel<<<dim3(2, 32, 16), 256, 0, stream>>>(Wk, wqT + E1,  1024, 64, 64, nullptr);
        // q,k (+RoPE)
        mfma_gemm<1><<<dim3(8, 16, 2), 256, 0, stream>>>(hB, wqT, qkbase, nullptr, S, 1024, 1024);
        // WvT over dead wq slot, then V^T direct
        tconv_kernel<<<dim3(2, 32, 16), 256, 0, stream>>>(Wv, wqT, 1024, 64, 64, nullptr);
        mfma_gemm<5><<<dim3(8, 16, 1), 256, 0, stream>>>(hB, wqT, vtb, nullptr, S, 1024, 1024);
    }

    // joint attention (1024 blocks)
    attn_kernel<<<dim3(32, 32), 256, 0, stream>>>(W, vt0, attnout);

    // Wo: x2 = x + attnout @ Wo   (joint M=4096)
    tconv_kernel<<<dim3(32, 32, 1), 256, 0, stream>>>(Wo, WoT, 1024, 1024, 1024, nullptr);
    mfma_gemm<2><<<dim3(8, 32, 1), 256, 0, stream>>>(attnout, WoT, x2, x, 4096, 1024, 1024);

    // LN2 stats + bias folds
    ln2stats_kernel<<<4096, 256, 0, stream>>>(x2, stats);
    biasw_kernel<<<8, 256, 0, stream>>>(ln2b, W1, bias1);
    biasw_kernel<<<8, 256, 0, stream>>>(ln2b, W2, bias2);

    // FFN in 4 N-quarters; final GEMMs write fp32 d_out (obB all-dead)
    for (int nh = 0; nh < 4; nh++) {
        tconv_kernel<<<dim3(16, 32, 1), 256, 0, stream>>>(W1 + nh * 512, W1q, 1024, 512, 2048, ln2g);
        tconv_kernel<<<dim3(16, 32, 1), 256, 0, stream>>>(W2 + nh * 512, W2q, 1024, 512, 2048, ln2g);
        dual_gemm_ln<<<dim3(8, 32, 1), 256, 0, stream>>>(
            x2, stats, W1q, W2q, bias1 + nh * 512, bias2 + nh * 512, sbq);
        tconv_kernel<<<dim3(32, 16, 1), 256, 0, stream>>>(W3 + (size_t)nh * 512 * 1024, W3q, 512, 1024, 1024, nullptr);
        if (nh == 0)
            mfma_gemm<4><<<dim3(8, 32, 1), 256, 0, stream>>>(sbq, W3q, out, x2, 4096, 1024, 512);
        else
            mfma_gemm<6><<<dim3(8, 32, 1), 256, 0, stream>>>(sbq, W3q, out, nullptr, 4096, 1024, 512);
    }
}

// Round 8
// 669.885 us; speedup vs baseline: 1.0085x; 1.0085x over previous
//
#include <hip/hip_runtime.h>
#include <hip/hip_bf16.h>

using bf16 = __hip_bfloat16;
typedef __attribute__((ext_vector_type(8))) short bf16x8;
typedef __attribute__((ext_vector_type(4))) float f32x4;

// Shapes fixed: B=2, S=2048, D=1024, H=16, hd=64, F=2048. Global I/O fp32.
// ws = 16 MB (8M bf16). d_out (16 MB) = obB scratch during QKV/attn, then
// holds x2 fp32 (written by Wo GEMM) and is RMW-accumulated by the FFN.
//
// QKV phase (per batch b):  ws: vt0[0:2M) vt1[2:4M) h[4:6M) wT[6:8M)
//                           obB: q0[0:2M) k0[2:4M) q1[4:6M) k1[6:8M)
// attn: reads obB q/k + ws vt -> attnout ws[4:8M)  (h/wT dead)
// Wo:   WoT -> ws[0:1M) (vt dead); mode7: d_out = attnout@Wo + x (fp32)
// ln2stats: d_out -> g_stats (device global)
// FFN per mh (rows mh*2048..): duals BOTH before finals (finals RMW only
//   rows mh; duals of other mh read disjoint rows -> no hazard):
//   W1h0->ws[0:1M) W2h0->ws[1:2M); dual(mh,0)->sb0 ws[3:5M)
//   W1h1->ws[0:1M) W2h1->ws[1:2M); dual(mh,1)->sb1 ws[5:7M)
//   W3h0->ws[2:3M); final(mh,0): d_out rows mh += sb0@W3h0
//   W3h1->ws[0:1M); final(mh,1): d_out rows mh += sb1@W3h1

__device__ float g_stats[8192];   // per-row {mu, rstd} for LN2, 4096 rows

__device__ inline float toF(float x) { return x; }
__device__ inline float toF(bf16 x) { return __bfloat162float(x); }

__device__ __forceinline__ void unpack8(uint4 u, float* f) {
    f[0] = __uint_as_float(u.x << 16); f[1] = __uint_as_float(u.x & 0xffff0000u);
    f[2] = __uint_as_float(u.y << 16); f[3] = __uint_as_float(u.y & 0xffff0000u);
    f[4] = __uint_as_float(u.z << 16); f[5] = __uint_as_float(u.z & 0xffff0000u);
    f[6] = __uint_as_float(u.w << 16); f[7] = __uint_as_float(u.w & 0xffff0000u);
}

__device__ __forceinline__ uint4 packbf8(const float* f) {
    union { unsigned short u[8]; uint4 v; } r;
#pragma unroll
    for (int i = 0; i < 8; i++) {
        bf16 b = __float2bfloat16(f[i]);
        r.u[i] = *(unsigned short*)&b;
    }
    return r.v;
}

__device__ __forceinline__ void gl_lds16(const void* g, void* l) {
    __builtin_amdgcn_global_load_lds(
        (__attribute__((address_space(1))) void*)g,
        (__attribute__((address_space(3))) void*)l, 16, 0, 0);
}

// ---------------------------------------------------------------------------
// LayerNorm (LN1): one block per row, D=1024. fp32 in -> bf16 out.
// ---------------------------------------------------------------------------
__global__ __launch_bounds__(256) void ln_kernel(
    const float* __restrict__ x, const float* __restrict__ g,
    const float* __restrict__ b, bf16* __restrict__ out)
{
    const int D = 1024;
    int row = blockIdx.x;
    int tid = threadIdx.x;
    const float* xr = x + (size_t)row * D;

    float vals[4];
    float sum = 0.f, sumsq = 0.f;
#pragma unroll
    for (int i = 0; i < 4; i++) {
        float v = xr[tid + i * 256];
        vals[i] = v; sum += v; sumsq += v * v;
    }
#pragma unroll
    for (int off = 32; off > 0; off >>= 1) {
        sum += __shfl_xor(sum, off);
        sumsq += __shfl_xor(sumsq, off);
    }
    __shared__ float s1[4], s2[4];
    int wave = tid >> 6, lane = tid & 63;
    if (lane == 0) { s1[wave] = sum; s2[wave] = sumsq; }
    __syncthreads();
    sum = s1[0] + s1[1] + s1[2] + s1[3];
    sumsq = s2[0] + s2[1] + s2[2] + s2[3];

    float mu = sum * (1.f / D);
    float var = sumsq * (1.f / D) - mu * mu;
    float rstd = rsqrtf(var + 1e-5f);

    bf16* orow = out + (size_t)row * D;
#pragma unroll
    for (int i = 0; i < 4; i++) {
        int c = tid + i * 256;
        orow[c] = __float2bfloat16((vals[i] - mu) * rstd * g[c] + b[c]);
    }
}

// ---------------------------------------------------------------------------
// LN2 stats from fp32 x2 (= d_out): g_stats[row] = {mu, rstd}
// ---------------------------------------------------------------------------
__global__ __launch_bounds__(256) void ln2stats_kernel(const float* __restrict__ x2)
{
    const int D = 1024;
    int row = blockIdx.x;
    int tid = threadIdx.x;
    const float* xr = x2 + (size_t)row * D;

    float sum = 0.f, sumsq = 0.f;
#pragma unroll
    for (int i = 0; i < 4; i++) {
        float v = xr[tid + i * 256];
        sum += v; sumsq += v * v;
    }
#pragma unroll
    for (int off = 32; off > 0; off >>= 1) {
        sum += __shfl_xor(sum, off);
        sumsq += __shfl_xor(sumsq, off);
    }
    __shared__ float s1[4], s2[4];
    int wave = tid >> 6, lane = tid & 63;
    if (lane == 0) { s1[wave] = sum; s2[wave] = sumsq; }
    __syncthreads();
    if (tid == 0) {
        sum = s1[0] + s1[1] + s1[2] + s1[3];
        sumsq = s2[0] + s2[1] + s2[2] + s2[3];
        float mu = sum * (1.f / D);
        float var = sumsq * (1.f / D) - mu * mu;
        g_stats[row * 2] = mu;
        g_stats[row * 2 + 1] = rsqrtf(var + 1e-5f);
    }
}

// ---------------------------------------------------------------------------
// Transpose+convert: in fp32, per z-slice [R][C] (row stride ldin) ->
// out bf16 [C][R].
// ---------------------------------------------------------------------------
__global__ __launch_bounds__(256) void tconv_kernel(
    const float* __restrict__ in, bf16* __restrict__ out,
    int R, int C, int ldin)
{
    __shared__ float t[32][33];
    int hh = blockIdx.z;
    const float* ip = in + (size_t)hh * R * ldin;
    bf16* op = out + (size_t)hh * C * R;
    int c0 = blockIdx.x * 32, r0 = blockIdx.y * 32;
    int tx = threadIdx.x & 31, ty = threadIdx.x >> 5;
#pragma unroll
    for (int i = 0; i < 4; i++)
        t[ty + 8 * i][tx] = ip[(size_t)(r0 + ty + 8 * i) * ldin + c0 + tx];
    __syncthreads();
#pragma unroll
    for (int i = 0; i < 4; i++)
        op[(size_t)(c0 + ty + 8 * i) * R + r0 + tx] = __float2bfloat16(t[tx][ty + 8 * i]);
}

// ---------------------------------------------------------------------------
// MFMA GEMM: C[M,N] = A[M,K](bf16) @ BT[N,K](bf16), fp32 accum.
// 128x128 tile, BK=32, 4 waves (2x2), 4x4 16x16 MFMA subtiles.
// MODE 1: QK+RoPE scatter (z in {0,1}: BT+=z<<20, C=Cbase+z<<21; [h][s][64])
// MODE 5: V^T scatter: Vt[h][kk][s] (packed 4-row 8B stores)
// MODE 6: C f32 += acc (in-place RMW)
// MODE 7: C f32  = acc + resF32
// ---------------------------------------------------------------------------
template <int MODE>
__global__ __launch_bounds__(256) void mfma_gemm(
    const bf16* __restrict__ A, const bf16* __restrict__ BT0,
    void* __restrict__ Cv, const void* __restrict__ resv,
    int M, int N, int K)
{
    __shared__ bf16 As[128 * 32];
    __shared__ bf16 Bs[128 * 32];
    int tid = threadIdx.x, lane = tid & 63, w = tid >> 6;
    int wm = w >> 1, wn = w & 1;
    int m0 = blockIdx.y * 128, n0 = blockIdx.x * 128;

    const bf16* BT = BT0;
    bf16* Cq = (bf16*)Cv;
    if (MODE == 1) {
        int z = blockIdx.z;
        BT = BT0 + ((size_t)z << 20);
        Cq = (bf16*)Cv + ((size_t)z << 21);
    }

    int srow = lane >> 2, scol = (lane & 3) * 8;
    const bf16* Ag = A + (size_t)(m0 + w * 32 + srow) * K + scol;
    const bf16* Bg = BT + (size_t)(n0 + w * 32 + srow) * K + scol;
    unsigned offAB = (unsigned)__builtin_amdgcn_readfirstlane(w * 2048);
    char* As_c = (char*)As;
    char* Bs_c = (char*)Bs;

    f32x4 acc[4][4];
#pragma unroll
    for (int i = 0; i < 4; i++)
#pragma unroll
        for (int j = 0; j < 4; j++) acc[i][j] = (f32x4){0.f, 0.f, 0.f, 0.f};

    for (int k0 = 0; k0 < K; k0 += 32) {
        gl_lds16(Ag + k0,                  As_c + offAB);
        gl_lds16(Ag + k0 + (size_t)16 * K, As_c + offAB + 1024);
        gl_lds16(Bg + k0,                  Bs_c + offAB);
        gl_lds16(Bg + k0 + (size_t)16 * K, Bs_c + offAB + 1024);
        __syncthreads();

        bf16x8 af[4], bfr[4];
#pragma unroll
        for (int i = 0; i < 4; i++)
            af[i] = *(const bf16x8*)&As[(wm * 64 + i * 16 + (lane & 15)) * 32 + (lane >> 4) * 8];
#pragma unroll
        for (int j = 0; j < 4; j++)
            bfr[j] = *(const bf16x8*)&Bs[(wn * 64 + j * 16 + (lane & 15)) * 32 + (lane >> 4) * 8];
#pragma unroll
        for (int i = 0; i < 4; i++)
#pragma unroll
            for (int j = 0; j < 4; j++)
                acc[i][j] = __builtin_amdgcn_mfma_f32_16x16x32_bf16(af[i], bfr[j], acc[i][j], 0, 0, 0);
        __syncthreads();
    }

    int rbase = (lane >> 4) * 4;
    int cidx = lane & 15;
#pragma unroll
    for (int i = 0; i < 4; i++) {
#pragma unroll
        for (int j = 0; j < 4; j++) {
            int col = n0 + wn * 64 + j * 16 + cidx;
            if (MODE == 5) {
                int h = col >> 6, kk = col & 63;
                int row0 = m0 + wm * 64 + i * 16 + rbase;
                union { unsigned short u[4]; uint2 v; } pk;
#pragma unroll
                for (int r = 0; r < 4; r++) {
                    bf16 bv = __float2bfloat16(acc[i][j][r]);
                    pk.u[r] = *(unsigned short*)&bv;
                }
                *(uint2*)(Cq + ((size_t)(h * 64 + kk) * 2048 + row0)) = pk.v;
            } else {
#pragma unroll
                for (int r = 0; r < 4; r++) {
                    int row = m0 + wm * 64 + i * 16 + rbase + r;
                    float v = acc[i][j][r];
                    size_t idx = (size_t)row * N + col;
                    if (MODE == 1) {
                        int h = col >> 6, kk = col & 63;
                        float other = __shfl_xor(v, 1);
                        float p = (float)(kk >> 1);
                        float theta = __expf(p * -0.5756462732485114f); // ln(1e4)/16
                        float ang = (float)row * theta;
                        float c, sn; __sincosf(ang, &sn, &c);
                        float outv = (kk & 1) ? (v * c + other * sn) : (v * c - other * sn);
                        Cq[((size_t)h * 2048 + row) * 64 + kk] = __float2bfloat16(outv);
                    } else if (MODE == 6) {
                        ((float*)Cv)[idx] += v;
                    } else { // MODE 7
                        v += ((const float*)resv)[idx];
                        ((float*)Cv)[idx] = v;
                    }
                }
            }
        }
    }
}

// ---------------------------------------------------------------------------
// Dual GEMM with fused LN2 A-staging (reads x2 fp32, normalizes w/ g_stats,
// applies gamma/beta) + SwiGLU epilogue.
// sb[2048,1024] = silu(hn@B1T) * (hn@B2T); hn = (x2-mu)*rstd*g + b.
// Tile 128m x 64n, BK=32, 4 waves 2x2 (wave 64m x 32n, 4x2 subtiles x2 B).
// ---------------------------------------------------------------------------
__global__ __launch_bounds__(256) void dual_gemm_ln(
    const float* __restrict__ x2f, int statsOff,
    const float* __restrict__ gvec, const float* __restrict__ bvec,
    const bf16* __restrict__ B1T, const bf16* __restrict__ B2T,
    bf16* __restrict__ sb)
{
    __shared__ bf16 As[128 * 40];
    __shared__ bf16 B1s[64 * 32];
    __shared__ bf16 B2s[64 * 32];
    __shared__ float gs[1024], bs[1024];
    int tid = threadIdx.x, lane = tid & 63, w = tid >> 6;
    int wm = w >> 1, wn = w & 1;
    int m0 = blockIdx.y * 128, n0 = blockIdx.x * 64;
    const int K = 1024;

    // preload gamma/beta to LDS
#pragma unroll
    for (int i = 0; i < 4; i++) {
        gs[tid + i * 256] = gvec[tid + i * 256];
        bs[tid + i * 256] = bvec[tid + i * 256];
    }

    int arow = tid >> 1, ah = tid & 1;
    int srow = lane >> 2, scol = (lane & 3) * 8;
    const bf16* B1g = B1T + (size_t)(n0 + w * 16 + srow) * K + scol;
    const bf16* B2g = B2T + (size_t)(n0 + w * 16 + srow) * K + scol;
    unsigned offB = (unsigned)__builtin_amdgcn_readfirstlane(w * 1024);
    char* B1s_c = (char*)B1s;
    char* B2s_c = (char*)B2s;

    float mu = g_stats[(statsOff + m0 + arow) * 2];
    float rs = g_stats[(statsOff + m0 + arow) * 2 + 1];
    const float* xrow = x2f + (size_t)(m0 + arow) * K;
    __syncthreads();   // gs/bs visible

    f32x4 acc1[4][2], acc2[4][2];
#pragma unroll
    for (int i = 0; i < 4; i++)
#pragma unroll
        for (int j = 0; j < 2; j++) {
            acc1[i][j] = (f32x4){0.f, 0.f, 0.f, 0.f};
            acc2[i][j] = (f32x4){0.f, 0.f, 0.f, 0.f};
        }

    for (int k0 = 0; k0 < K; k0 += 32) {
        int c0 = k0 + ah * 16;
        float f[16];
        const float4* xs = (const float4*)(xrow + c0);
#pragma unroll
        for (int t = 0; t < 4; t++) {
            float4 v4 = xs[t];
            f[4 * t] = v4.x; f[4 * t + 1] = v4.y; f[4 * t + 2] = v4.z; f[4 * t + 3] = v4.w;
        }
        gl_lds16(B1g + k0, B1s_c + offB);
        gl_lds16(B2g + k0, B2s_c + offB);
#pragma unroll
        for (int t = 0; t < 4; t++) {
            float4 g4 = *(const float4*)&gs[c0 + 4 * t];
            float4 b4 = *(const float4*)&bs[c0 + 4 * t];
            f[4 * t]     = (f[4 * t]     - mu) * rs * g4.x + b4.x;
            f[4 * t + 1] = (f[4 * t + 1] - mu) * rs * g4.y + b4.y;
            f[4 * t + 2] = (f[4 * t + 2] - mu) * rs * g4.z + b4.z;
            f[4 * t + 3] = (f[4 * t + 3] - mu) * rs * g4.w + b4.w;
        }
        uint4 p0 = packbf8(f), p1 = packbf8(f + 8);
        *(uint4*)&As[arow * 40 + ah * 16] = p0;
        *(uint4*)&As[arow * 40 + ah * 16 + 8] = p1;
        __syncthreads();

        bf16x8 af[4], b1f[2], b2f[2];
#pragma unroll
        for (int i = 0; i < 4; i++)
            af[i] = *(const bf16x8*)&As[(wm * 64 + i * 16 + (lane & 15)) * 40 + (lane >> 4) * 8];
#pragma unroll
        for (int j = 0; j < 2; j++) {
            b1f[j] = *(const bf16x8*)&B1s[(wn * 32 + j * 16 + (lane & 15)) * 32 + (lane >> 4) * 8];
            b2f[j] = *(const bf16x8*)&B2s[(wn * 32 + j * 16 + (lane & 15)) * 32 + (lane >> 4) * 8];
        }
#pragma unroll
        for (int i = 0; i < 4; i++)
#pragma unroll
            for (int j = 0; j < 2; j++) {
                acc1[i][j] = __builtin_amdgcn_mfma_f32_16x16x32_bf16(af[i], b1f[j], acc1[i][j], 0, 0, 0);
                acc2[i][j] = __builtin_amdgcn_mfma_f32_16x16x32_bf16(af[i], b2f[j], acc2[i][j], 0, 0, 0);
            }
        __syncthreads();
    }

    int rbase = (lane >> 4) * 4;
    int cidx = lane & 15;
#pragma unroll
    for (int i = 0; i < 4; i++) {
#pragma unroll
        for (int j = 0; j < 2; j++) {
            int col = n0 + wn * 32 + j * 16 + cidx;
#pragma unroll
            for (int r = 0; r < 4; r++) {
                int row = m0 + wm * 64 + i * 16 + rbase + r;
                float u = acc1[i][j][r];
                float sg = 1.f / (1.f + __expf(-u));
                sb[(size_t)row * 1024 + col] = __float2bfloat16(u * sg * acc2[i][j][r]);
            }
        }
    }
}

// ---------------------------------------------------------------------------
// MFMA causal flash attention, joint batches, fixed-max softmax.
// q,k from qk base (obB): q_b at +b*4M, k_b at +b*4M+2M; vt: [b][16][64][2048].
// out: attnout [4096][1024] bf16 (row = b*2048+s).
// ---------------------------------------------------------------------------
__global__ __launch_bounds__(256) void attn_kernel(
    const bf16* __restrict__ qk, const bf16* __restrict__ vt,
    bf16* __restrict__ o)
{
    const int S = 2048;
    __shared__ bf16 Ks[64][72];
    __shared__ bf16 Vs[64][72];
    __shared__ __align__(16) char QPbuf[64 * 72 * 2];
    bf16 (*Qs)[72] = (bf16 (*)[72])QPbuf;
    bf16 (*Ps)[16][72] = (bf16 (*)[16][72])QPbuf;

    int qt = 31 - (int)blockIdx.x;
    int bh = blockIdx.y;
    int b = bh >> 4, h = bh & 15;
    int tid = threadIdx.x, lane = tid & 63, w = tid >> 6;
    int quad = lane >> 4, cidx = lane & 15;
    int m0 = qt * 64;

    const bf16* qb = qk + ((size_t)b << 22) + ((size_t)h * S + m0) * 64;
    const bf16* kb = qk + ((size_t)b << 22) + (2u << 20) + (size_t)h * S * 64;
    const bf16* vtb = vt + ((size_t)b << 21) + (size_t)h * 64 * S;

    int srow = tid >> 2;
    int sg = (tid & 3) * 16;

    {
        const uint4* src = (const uint4*)(qb + (size_t)srow * 64 + sg);
        uint4 u0 = src[0], u1 = src[1];
        float f[16]; unpack8(u0, f); unpack8(u1, f + 8);
#pragma unroll
        for (int i = 0; i < 16; i++) f[i] *= 0.125f;
        *(uint4*)&Qs[srow][sg] = packbf8(f);
        *(uint4*)&Qs[srow][sg + 8] = packbf8(f + 8);
    }
    __syncthreads();

    bf16x8 aQ0 = *(const bf16x8*)&Qs[w * 16 + cidx][quad * 8];
    bf16x8 aQ1 = *(const bf16x8*)&Qs[w * 16 + cidx][32 + quad * 8];

    float l_i[4];
    f32x4 Oc[4];
#pragma unroll
    for (int r = 0; r < 4; r++) l_i[r] = 0.f;
#pragma unroll
    for (int j = 0; j < 4; j++) Oc[j] = (f32x4){0.f, 0.f, 0.f, 0.f};

    for (int kt = 0; kt <= qt; kt++) {
        const uint4* ksrc = (const uint4*)(kb + ((size_t)(kt * 64 + srow)) * 64 + sg);
        uint4 ka0 = ksrc[0], ka1 = ksrc[1];
        const uint4* vsrc = (const uint4*)(vtb + (size_t)srow * S + kt * 64 + sg);
        uint4 va0 = vsrc[0], va1 = vsrc[1];

        __syncthreads();
        *(uint4*)&Ks[srow][sg] = ka0; *(uint4*)&Ks[srow][sg + 8] = ka1;
        *(uint4*)&Vs[srow][sg] = va0; *(uint4*)&Vs[srow][sg + 8] = va1;
        __syncthreads();

        f32x4 sc[4];
#pragma unroll
        for (int j = 0; j < 4; j++) sc[j] = (f32x4){0.f, 0.f, 0.f, 0.f};
#pragma unroll
        for (int j = 0; j < 4; j++) {
            bf16x8 bk0 = *(const bf16x8*)&Ks[j * 16 + cidx][quad * 8];
            bf16x8 bk1 = *(const bf16x8*)&Ks[j * 16 + cidx][32 + quad * 8];
            sc[j] = __builtin_amdgcn_mfma_f32_16x16x32_bf16(aQ0, bk0, sc[j], 0, 0, 0);
            sc[j] = __builtin_amdgcn_mfma_f32_16x16x32_bf16(aQ1, bk1, sc[j], 0, 0, 0);
        }

        if (kt == qt) {
#pragma unroll
            for (int j = 0; j < 4; j++)
#pragma unroll
                for (int r = 0; r < 4; r++)
                    if (j * 16 + cidx > w * 16 + quad * 4 + r) sc[j][r] = -INFINITY;
        }

#pragma unroll
        for (int j = 0; j < 4; j++) {
#pragma unroll
            for (int r = 0; r < 4; r++) {
                float p = __expf(sc[j][r]);
                l_i[r] += p;
                Ps[w][quad * 4 + r][j * 16 + cidx] = __float2bfloat16(p);
            }
        }

        bf16x8 aP0 = *(const bf16x8*)&Ps[w][cidx][quad * 8];
        bf16x8 aP1 = *(const bf16x8*)&Ps[w][cidx][32 + quad * 8];
#pragma unroll
        for (int j = 0; j < 4; j++) {
            bf16x8 bv0 = *(const bf16x8*)&Vs[j * 16 + cidx][quad * 8];
            bf16x8 bv1 = *(const bf16x8*)&Vs[j * 16 + cidx][32 + quad * 8];
            Oc[j] = __builtin_amdgcn_mfma_f32_16x16x32_bf16(aP0, bv0, Oc[j], 0, 0, 0);
            Oc[j] = __builtin_amdgcn_mfma_f32_16x16x32_bf16(aP1, bv1, Oc[j], 0, 0, 0);
        }
    }

#pragma unroll
    for (int r = 0; r < 4; r++) {
        float l = l_i[r];
        l += __shfl_xor(l, 1);
        l += __shfl_xor(l, 2);
        l += __shfl_xor(l, 4);
        l += __shfl_xor(l, 8);
        float inv = 1.f / l;
        int row = b * 2048 + m0 + w * 16 + quad * 4 + r;
#pragma unroll
        for (int j = 0; j < 4; j++)
            o[(size_t)row * 1024 + h * 64 + j * 16 + cidx] = __float2bfloat16(Oc[j][r] * inv);
    }
}

// ---------------------------------------------------------------------------
extern "C" void kernel_launch(void* const* d_in, const int* in_sizes, int n_in,
                              void* d_out, int out_size, void* d_ws, size_t ws_size,
                              hipStream_t stream)
{
    const int S = 2048;
    const size_t E1 = 1u << 20;        // 1M elems

    const float* x    = (const float*)d_in[0];
    const float* ln1g = (const float*)d_in[1];
    const float* ln1b = (const float*)d_in[2];
    const float* Wq   = (const float*)d_in[3];
    const float* Wk   = (const float*)d_in[4];
    const float* Wv   = (const float*)d_in[5];
    const float* Wo   = (const float*)d_in[6];
    const float* ln2g = (const float*)d_in[7];
    const float* ln2b = (const float*)d_in[8];
    const float* W1   = (const float*)d_in[9];
    const float* W2   = (const float*)d_in[10];
    const float* W3   = (const float*)d_in[11];
    float* out = (float*)d_out;

    bf16* W = (bf16*)d_ws;             // 8M elems
    bf16* obB = (bf16*)d_out;          // 8M elems, scratch until Wo

    bf16* hB = W + 4 * E1;             // [4M:6M)
    bf16* wT = W + 6 * E1;             // [6M:8M)
    bf16* attnout = W + 4 * E1;        // [4M:8M) after attn

    // ---- QKV phase (per batch) ----
    for (int b = 0; b < 2; b++) {
        const float* xb = x + (size_t)b * S * 1024;
        bf16* qkb = obB + (size_t)b * 4 * E1;    // q at +0, k at +2M
        bf16* vtb = W + (size_t)b * 2 * E1;

        ln_kernel<<<S, 256, 0, stream>>>(xb, ln1g, ln1b, hB);
        tconv_kernel<<<dim3(2, 32, 16), 256, 0, stream>>>(Wq, wT,      1024, 64, 64);
        tconv_kernel<<<dim3(2, 32, 16), 256, 0, stream>>>(Wk, wT + E1, 1024, 64, 64);
        mfma_gemm<1><<<dim3(8, 16, 2), 256, 0, stream>>>(hB, wT, qkb, nullptr, S, 1024, 1024);
        tconv_kernel<<<dim3(2, 32, 16), 256, 0, stream>>>(Wv, wT, 1024, 64, 64);
        mfma_gemm<5><<<dim3(8, 16, 1), 256, 0, stream>>>(hB, wT, vtb, nullptr, S, 1024, 1024);
    }

    // ---- joint attention: obB q/k + ws vt -> attnout (ws) ----
    attn_kernel<<<dim3(32, 32), 256, 0, stream>>>(obB, W, attnout);

    // ---- Wo: d_out(fp32) = attnout @ Wo + x ----
    tconv_kernel<<<dim3(32, 32, 1), 256, 0, stream>>>(Wo, W, 1024, 1024, 1024);   // WoT -> ws[0:1M)
    mfma_gemm<7><<<dim3(8, 32, 1), 256, 0, stream>>>(attnout, W, out, x, 4096, 1024, 1024);

    // ---- LN2 stats ----
    ln2stats_kernel<<<4096, 256, 0, stream>>>(out);

    // ---- FFN: M-halves x N-halves ----
    bf16* w1s = W;                     // [0:1M)
    bf16* w2s = W + E1;                // [1:2M)
    bf16* w3a = W + 2 * E1;            // [2:3M)
    bf16* sb0 = W + 3 * E1;            // [3:5M)
    bf16* sb1 = W + 5 * E1;            // [5:7M)

    for (int mh = 0; mh < 2; mh++) {
        float* x2h = out + (size_t)mh * 2048 * 1024;
        // both duals before any final (finals modify d_out rows mh only)
        tconv_kernel<<<dim3(32, 32, 1), 256, 0, stream>>>(W1, w1s, 1024, 1024, 2048);
        tconv_kernel<<<dim3(32, 32, 1), 256, 0, stream>>>(W2, w2s, 1024, 1024, 2048);
        dual_gemm_ln<<<dim3(16, 16), 256, 0, stream>>>(x2h, mh * 2048, ln2g, ln2b, w1s, w2s, sb0);
        tconv_kernel<<<dim3(32, 32, 1), 256, 0, stream>>>(W1 + 1024, w1s, 1024, 1024, 2048);
        tconv_kernel<<<dim3(32, 32, 1), 256, 0, stream>>>(W2 + 1024, w2s, 1024, 1024, 2048);
        dual_gemm_ln<<<dim3(16, 16), 256, 0, stream>>>(x2h, mh * 2048, ln2g, ln2b, w1s, w2s, sb1);
        // finals: d_out rows mh += sb@W3h  (K-split RMW)
        tconv_kernel<<<dim3(32, 32, 1), 256, 0, stream>>>(W3, w3a, 1024, 1024, 1024);
        mfma_gemm<6><<<dim3(8, 16, 1), 256, 0, stream>>>(sb0, w3a, x2h, nullptr, 2048, 1024, 1024);
        tconv_kernel<<<dim3(32, 32, 1), 256, 0, stream>>>(W3 + (size_t)1024 * 1024, w1s, 1024, 1024, 1024);
        mfma_gemm<6><<<dim3(8, 16, 1), 256, 0, stream>>>(sb1, w1s, x2h, nullptr, 2048, 1024, 1024);
    }
}